// Round 8
// baseline (312.315 us; speedup 1.0000x reference)
//
#include <hip/hip_runtime.h>
#include <hip/hip_bf16.h>

// ---------------------------------------------------------------------------
// GCN 4-layer forward on MI355X.
//   - R6: single-pass SLOTTED CSR build (one device atomic per (bin,tile)).
//   - R6: k_w4 fused into agg3 (h3 never materialized).
//   - R5: float4 gathers (D/4 lanes/node), agg epilogue fusion.
//   - R7: GEMM microtile 4x4 -> 8x8 (L1) / 8x4 (L2). 4x4 was LDS-BW-bound:
//     1 B/FLOP vs ~112 B/cyc/CU LDS port => ~69 TF ceiling. 8x8 halves
//     LDS bytes/FLOP -> FMA-bound (~157 TF vector peak).
//   - R7: k_agg 8-edge unroll (mean deg = 8).
//   - pool: wave segmented scan on sorted gid (R1: contended atomics 152us).
// ---------------------------------------------------------------------------

#define TILE 4096   // edges per build tile (256 threads x 16)
#define SLOT 8192   // per-bin slot capacity (bin = 512 nodes, mean ~4080 edges)

// --- build pass 1: tile->LDS, histogram, reserve slot space, scatter -------
__global__ __launch_bounds__(256) void k_buildbins(
        const int* __restrict__ src, const int* __restrict__ dst, int E, int NBIN,
        int* __restrict__ cntD, int* __restrict__ cntS,
        int* __restrict__ bucketD, unsigned short* __restrict__ bucketS) {
    __shared__ int ssrc[TILE];
    __shared__ int sdst[TILE];
    __shared__ int hD[256], hS[256], bD[256], bS[256];
    int t = threadIdx.x;
    hD[t] = 0; hS[t] = 0;
    __syncthreads();
    int base = blockIdx.x * TILE;
    int lim = min(TILE, E - base);
#pragma unroll
    for (int k = 0; k < TILE / 256; k++) {
        int i = k * 256 + t;
        if (i < lim) {
            int d = dst[base + i], sv = src[base + i];
            sdst[i] = d; ssrc[i] = sv;
            atomicAdd(&hD[d >> 9], 1);
            atomicAdd(&hS[sv >> 9], 1);
        }
    }
    __syncthreads();
    if (t < NBIN) {
        bD[t] = (hD[t] > 0) ? atomicAdd(&cntD[t], hD[t]) : 0;
        bS[t] = (hS[t] > 0) ? atomicAdd(&cntS[t], hS[t]) : 0;
        hD[t] = 0; hS[t] = 0;
    }
    __syncthreads();
#pragma unroll
    for (int k = 0; k < TILE / 256; k++) {
        int i = k * 256 + t;
        if (i < lim) {
            int d = sdst[i], sv = ssrc[i];
            int binD = d >> 9, binS = sv >> 9;
            int pD = atomicAdd(&hD[binD], 1) + bD[binD];
            bucketD[binD * SLOT + pD] = (sv << 9) | (d & 511);
            int pS = atomicAdd(&hS[binS], 1) + bS[binS];
            bucketS[binS * SLOT + pS] = (unsigned short)(sv & 511);
        }
    }
}

// --- build pass 2: per-src-bucket LDS count -> norm_out --------------------
__global__ __launch_bounds__(256) void k_degout(const unsigned short* __restrict__ bucketS,
                                                const int* __restrict__ cntS,
                                                int N, float* __restrict__ norm_out) {
    __shared__ int cnt[512];
    int t = threadIdx.x;
    cnt[t] = 0; cnt[t + 256] = 0;
    __syncthreads();
    int bin = blockIdx.x;
    int b0 = bin * SLOT, cn = cntS[bin];
    for (int j = t; j < cn; j += 256) atomicAdd(&cnt[bucketS[b0 + j]], 1);
    __syncthreads();
    int base = bin << 9;
    for (int l = t; l < 512; l += 256) {
        int g = base + l;
        if (g < N) norm_out[g] = rsqrtf(fmaxf((float)cnt[l], 1.0f));
    }
}

// --- build pass 3: per-dst-bucket count+scan -> rowBE/norm_in, place edges -
__global__ __launch_bounds__(256) void k_build(const int* __restrict__ bucketD,
                                               const int* __restrict__ cntDg,
                                               const float* __restrict__ norm_out,
                                               int N, int2* __restrict__ rowBE,
                                               float* __restrict__ norm_in,
                                               int2* __restrict__ edges) {
    __shared__ int cnt[512], sc[512];
    int t = threadIdx.x;
    cnt[t] = 0; cnt[t + 256] = 0;
    __syncthreads();
    int bin = blockIdx.x;
    int b0 = bin * SLOT, cn = cntDg[bin];
    for (int j = t; j < cn; j += 256) atomicAdd(&cnt[bucketD[b0 + j] & 511], 1);
    __syncthreads();
    sc[t] = cnt[t]; sc[t + 256] = cnt[t + 256];
    __syncthreads();
    for (int off = 1; off < 512; off <<= 1) {
        int v0 = (t >= off) ? sc[t - off] : 0;
        int i1 = t + 256;
        int v1 = sc[i1 - off];   // i1 >= 256 >= off always
        __syncthreads();
        sc[t] += v0; sc[i1] += v1;
        __syncthreads();
    }
    int base = bin << 9;
    for (int l = t; l < 512; l += 256) {
        int g = base + l;
        int e = sc[l] - cnt[l];          // exclusive within bucket
        if (g < N) {
            rowBE[g] = make_int2(b0 + e, b0 + sc[l]);
            norm_in[g] = rsqrtf(fmaxf((float)cnt[l], 1.0f));
        }
        cnt[l] = e;                      // becomes placement cursor
    }
    __syncthreads();
    for (int j = t; j < cn; j += 256) {
        int p = bucketD[b0 + j];
        int sv = p >> 9, dl = p & 511;
        int pos = atomicAdd(&cnt[dl], 1);
        edges[b0 + pos] = make_int2(sv, __float_as_int(norm_out[sv]));
    }
}

// gather aggregation, float4 lanes: G = D/4 lanes per node, 8-edge unroll.
// EPI: out = relu(acc * norm[node] + bias4[lane])
template <int D, bool EPI>
__global__ __launch_bounds__(256) void k_agg(const float4* __restrict__ h4,
                                             const int2* __restrict__ edges,
                                             const int2* __restrict__ rowBE, int n,
                                             float4* __restrict__ out4,
                                             const float* __restrict__ norm,
                                             const float4* __restrict__ bias4) {
    constexpr int G = D / 4;           // lanes per node
    const int per = 256 / G;           // nodes per block
    int node = blockIdx.x * per + threadIdx.x / G;
    int lane = threadIdx.x % G;
    if (node >= n) return;
    int2 be = rowBE[node];
    int j = be.x, end = be.y;
    float4 acc = make_float4(0.f, 0.f, 0.f, 0.f);
    for (; j + 7 < end; j += 8) {
        int2 e[8];
        float4 v[8];
#pragma unroll
        for (int q = 0; q < 8; q++) e[q] = edges[j + q];
#pragma unroll
        for (int q = 0; q < 8; q++) v[q] = h4[(size_t)e[q].x * G + lane];
#pragma unroll
        for (int q = 0; q < 8; q++) {
            float wq = __int_as_float(e[q].y);
            acc.x += v[q].x * wq;
            acc.y += v[q].y * wq;
            acc.z += v[q].z * wq;
            acc.w += v[q].w * wq;
        }
    }
    if (j + 3 < end) {
        int2 e0 = edges[j];
        int2 e1 = edges[j + 1];
        int2 e2 = edges[j + 2];
        int2 e3 = edges[j + 3];
        float4 v0 = h4[(size_t)e0.x * G + lane];
        float4 v1 = h4[(size_t)e1.x * G + lane];
        float4 v2 = h4[(size_t)e2.x * G + lane];
        float4 v3 = h4[(size_t)e3.x * G + lane];
        float w0 = __int_as_float(e0.y), w1 = __int_as_float(e1.y);
        float w2 = __int_as_float(e2.y), w3 = __int_as_float(e3.y);
        acc.x += v0.x * w0 + v1.x * w1 + v2.x * w2 + v3.x * w3;
        acc.y += v0.y * w0 + v1.y * w1 + v2.y * w2 + v3.y * w3;
        acc.z += v0.z * w0 + v1.z * w1 + v2.z * w2 + v3.z * w3;
        acc.w += v0.w * w0 + v1.w * w1 + v2.w * w2 + v3.w * w3;
        j += 4;
    }
    for (; j < end; j++) {
        int2 e = edges[j];
        float4 v = h4[(size_t)e.x * G + lane];
        float w0 = __int_as_float(e.y);
        acc.x += v.x * w0; acc.y += v.y * w0; acc.z += v.z * w0; acc.w += v.w * w0;
    }
    if (EPI) {
        float s = norm[node];
        float4 b = bias4[lane];
        acc.x = fmaxf(acc.x * s + b.x, 0.f);
        acc.y = fmaxf(acc.y * s + b.y, 0.f);
        acc.z = fmaxf(acc.z * s + b.z, 0.f);
        acc.w = fmaxf(acc.w * s + b.w, 0.f);
    }
    out4[(size_t)node * G + lane] = acc;
}

// agg3 + W4 fused (D=32): h3 = relu(agg(t3)*norm+b3) in regs (never stored),
// t4[node] = h3 @ W4 via per-lane partials + 8-lane __shfl_xor reduce.
__global__ __launch_bounds__(256) void k_aggw4(const float4* __restrict__ h4,
                        const int2* __restrict__ edges, const int2* __restrict__ rowBE,
                        const float* __restrict__ norm, const float4* __restrict__ b3_4,
                        const float* __restrict__ W4, int n, float4* __restrict__ t4) {
    __shared__ float w[128];
    if (threadIdx.x < 128) w[threadIdx.x] = W4[threadIdx.x];
    __syncthreads();
    int node = blockIdx.x * 32 + threadIdx.x / 8;
    int lane = threadIdx.x % 8;
    if (node >= n) return;
    float4 wr0 = ((const float4*)w)[4 * lane + 0];
    float4 wr1 = ((const float4*)w)[4 * lane + 1];
    float4 wr2 = ((const float4*)w)[4 * lane + 2];
    float4 wr3 = ((const float4*)w)[4 * lane + 3];
    int2 be = rowBE[node];
    int j = be.x, end = be.y;
    float4 acc = make_float4(0.f, 0.f, 0.f, 0.f);
    for (; j + 3 < end; j += 4) {
        int2 e0 = edges[j];
        int2 e1 = edges[j + 1];
        int2 e2 = edges[j + 2];
        int2 e3 = edges[j + 3];
        float4 v0 = h4[(size_t)e0.x * 8 + lane];
        float4 v1 = h4[(size_t)e1.x * 8 + lane];
        float4 v2 = h4[(size_t)e2.x * 8 + lane];
        float4 v3 = h4[(size_t)e3.x * 8 + lane];
        float w0 = __int_as_float(e0.y), w1 = __int_as_float(e1.y);
        float w2 = __int_as_float(e2.y), w3 = __int_as_float(e3.y);
        acc.x += v0.x * w0 + v1.x * w1 + v2.x * w2 + v3.x * w3;
        acc.y += v0.y * w0 + v1.y * w1 + v2.y * w2 + v3.y * w3;
        acc.z += v0.z * w0 + v1.z * w1 + v2.z * w2 + v3.z * w3;
        acc.w += v0.w * w0 + v1.w * w1 + v2.w * w2 + v3.w * w3;
    }
    for (; j < end; j++) {
        int2 e = edges[j];
        float4 v = h4[(size_t)e.x * 8 + lane];
        float w0 = __int_as_float(e.y);
        acc.x += v.x * w0; acc.y += v.y * w0; acc.z += v.z * w0; acc.w += v.w * w0;
    }
    float s = norm[node];
    float4 b = b3_4[lane];
    float hx = fmaxf(acc.x * s + b.x, 0.f);
    float hy = fmaxf(acc.y * s + b.y, 0.f);
    float hz = fmaxf(acc.z * s + b.z, 0.f);
    float hw = fmaxf(acc.w * s + b.w, 0.f);
    float4 p;
    p.x = hx * wr0.x + hy * wr1.x + hz * wr2.x + hw * wr3.x;
    p.y = hx * wr0.y + hy * wr1.y + hz * wr2.y + hw * wr3.y;
    p.z = hx * wr0.z + hy * wr1.z + hz * wr2.z + hw * wr3.z;
    p.w = hx * wr0.w + hy * wr1.w + hz * wr2.w + hw * wr3.w;
#pragma unroll
    for (int m = 1; m < 8; m <<= 1) {
        p.x += __shfl_xor(p.x, m);
        p.y += __shfl_xor(p.y, m);
        p.z += __shfl_xor(p.z, m);
        p.w += __shfl_xor(p.w, m);
    }
    if (lane == 0) t4[node] = p;
}

// out[N x M] = op(A[N x K] (opt row-scaled)) @ W[K x M] (+bias, relu).
// MR x MC microtile per thread (R7: 8x8 halves LDS bytes/FLOP vs 4x4).
template <int K, int M, int MR, int MC, bool PRESCALE, bool BIAS_RELU>
__global__ __launch_bounds__(256) void k_gemm(const float* __restrict__ A,
                                              const float* __restrict__ W,
                                              const float* __restrict__ bias,
                                              const float* __restrict__ norm, int N,
                                              float* __restrict__ out) {
    constexpr int CT   = M / MC;       // col threads
    constexpr int RTH  = 256 / CT;     // row threads
    constexpr int ROWS = RTH * MR;     // rows per block
    constexpr int KC   = (K > 64) ? 64 : K;
    constexpr int APAD = ROWS + 4;
    __shared__ float Alds[KC * APAD];  // transposed: Alds[k][r]
    __shared__ float Wlds[KC * M];
    int t  = threadIdx.x;
    int tx = t % CT;
    int ty = t / CT;
    int row0 = blockIdx.x * ROWS;
    float acc[MR][MC] = {};
    for (int kc = 0; kc < K; kc += KC) {
        for (int idx = t; idx < KC * M / 4; idx += 256)
            ((float4*)Wlds)[idx] = ((const float4*)(W + kc * M))[idx];
        constexpr int A4 = ROWS * KC / 4;
        for (int idx = t; idx < A4; idx += 256) {
            int r  = idx / (KC / 4);
            int k4 = idx % (KC / 4);
            int grow = row0 + r;
            float4 v = make_float4(0.f, 0.f, 0.f, 0.f);
            if (grow < N) {
                v = *(const float4*)(A + (size_t)grow * K + kc + k4 * 4);
                if (PRESCALE) {
                    float s = norm[grow];
                    v.x *= s; v.y *= s; v.z *= s; v.w *= s;
                }
            }
            Alds[(k4 * 4 + 0) * APAD + r] = v.x;
            Alds[(k4 * 4 + 1) * APAD + r] = v.y;
            Alds[(k4 * 4 + 2) * APAD + r] = v.z;
            Alds[(k4 * 4 + 3) * APAD + r] = v.w;
        }
        __syncthreads();
#pragma unroll 4
        for (int k = 0; k < KC; k++) {
            float a[MR], w[MC];
#pragma unroll
            for (int i = 0; i < MR / 4; i++)
                *(float4*)&a[4 * i] = *(const float4*)&Alds[k * APAD + ty * MR + 4 * i];
#pragma unroll
            for (int jq = 0; jq < MC / 4; jq++)
                *(float4*)&w[4 * jq] = *(const float4*)&Wlds[k * M + tx * MC + 4 * jq];
#pragma unroll
            for (int i = 0; i < MR; i++) {
#pragma unroll
                for (int jj = 0; jj < MC; jj++) acc[i][jj] += a[i] * w[jj];
            }
        }
        __syncthreads();
    }
#pragma unroll
    for (int i = 0; i < MR; i++) {
        int grow = row0 + ty * MR + i;
        if (grow < N) {
#pragma unroll
            for (int jq = 0; jq < MC / 4; jq++) {
                float4 o = make_float4(acc[i][4 * jq + 0], acc[i][4 * jq + 1],
                                       acc[i][4 * jq + 2], acc[i][4 * jq + 3]);
                if (BIAS_RELU) {
                    float4 b = *(const float4*)(bias + tx * MC + 4 * jq);
                    o.x = fmaxf(o.x + b.x, 0.f);
                    o.y = fmaxf(o.y + b.y, 0.f);
                    o.z = fmaxf(o.z + b.z, 0.f);
                    o.w = fmaxf(o.w + b.w, 0.f);
                }
                *(float4*)(out + (size_t)grow * M + tx * MC + 4 * jq) = o;
            }
        }
    }
}

// L4 fused: per node (1 thread): acc = sum_e t4[src_e]*norm_out_e ;
// v = acc*norm_in + b4 ; wave segmented-scan pool on sorted gid -> atomics
__global__ __launch_bounds__(256) void k_aggpool(const float4* __restrict__ t4,
                        const int2* __restrict__ edges, const int2* __restrict__ rowBE,
                        const float* __restrict__ norm, const float* __restrict__ b4,
                        const int* __restrict__ gid, int N,
                        float* __restrict__ sums, float* __restrict__ counts) {
    int n = blockIdx.x * blockDim.x + threadIdx.x;
    int lane = threadIdx.x & 63;
    bool valid = (n < N);
    float v0 = 0.f, v1 = 0.f, v2 = 0.f, v3 = 0.f, cnt = 0.f;
    int g = -1;
    if (valid) {
        g = gid[n];
        int2 be = rowBE[n];
        int j = be.x, end = be.y;
        float4 acc = make_float4(0.f, 0.f, 0.f, 0.f);
        for (; j + 3 < end; j += 4) {
            int2 e0 = edges[j];
            int2 e1 = edges[j + 1];
            int2 e2 = edges[j + 2];
            int2 e3 = edges[j + 3];
            float4 x0 = t4[e0.x];
            float4 x1 = t4[e1.x];
            float4 x2 = t4[e2.x];
            float4 x3 = t4[e3.x];
            float w0 = __int_as_float(e0.y), w1 = __int_as_float(e1.y);
            float w2 = __int_as_float(e2.y), w3 = __int_as_float(e3.y);
            acc.x += x0.x * w0 + x1.x * w1 + x2.x * w2 + x3.x * w3;
            acc.y += x0.y * w0 + x1.y * w1 + x2.y * w2 + x3.y * w3;
            acc.z += x0.z * w0 + x1.z * w1 + x2.z * w2 + x3.z * w3;
            acc.w += x0.w * w0 + x1.w * w1 + x2.w * w2 + x3.w * w3;
        }
        for (; j < end; j++) {
            int2 e = edges[j];
            float4 x = t4[e.x];
            float w0 = __int_as_float(e.y);
            acc.x += x.x * w0; acc.y += x.y * w0; acc.z += x.z * w0; acc.w += x.w * w0;
        }
        float s = norm[n];
        v0 = acc.x * s + b4[0];
        v1 = acc.y * s + b4[1];
        v2 = acc.z * s + b4[2];
        v3 = acc.w * s + b4[3];
        cnt = 1.f;
    }
    // segmented inclusive scan across the 64-lane wave (gid sorted)
#pragma unroll
    for (int off = 1; off < 64; off <<= 1) {
        float u0 = __shfl_up(v0, off);
        float u1 = __shfl_up(v1, off);
        float u2 = __shfl_up(v2, off);
        float u3 = __shfl_up(v3, off);
        float uc = __shfl_up(cnt, off);
        int   ug = __shfl_up(g, off);
        if (lane >= off && ug == g) { v0 += u0; v1 += u1; v2 += u2; v3 += u3; cnt += uc; }
    }
    int gnext = __shfl_down(g, 1);
    bool boundary = (lane == 63) || (gnext != g);
    if (boundary && valid) {
        atomicAdd(&sums[g * 4 + 0], v0);
        atomicAdd(&sums[g * 4 + 1], v1);
        atomicAdd(&sums[g * 4 + 2], v2);
        atomicAdd(&sums[g * 4 + 3], v3);
        atomicAdd(&counts[g], cnt);
    }
}

__global__ void k_div(const float* __restrict__ sums, const float* __restrict__ counts,
                      int G, float* __restrict__ out) {
    int idx = blockIdx.x * blockDim.x + threadIdx.x;
    if (idx >= G * 4) return;
    out[idx] = sums[idx] / fmaxf(counts[idx >> 2], 1.0f);
}

extern "C" void kernel_launch(void* const* d_in, const int* in_sizes, int n_in,
                              void* d_out, int out_size, void* d_ws, size_t ws_size,
                              hipStream_t stream) {
    const float* x  = (const float*)d_in[0];
    const float* W1 = (const float*)d_in[1];
    const float* b1 = (const float*)d_in[2];
    const float* W2 = (const float*)d_in[3];
    const float* b2 = (const float*)d_in[4];
    const float* W3 = (const float*)d_in[5];
    const float* b3 = (const float*)d_in[6];
    const float* W4 = (const float*)d_in[7];
    const float* b4 = (const float*)d_in[8];
    const int* src = (const int*)d_in[9];
    const int* dst = (const int*)d_in[10];
    const int* gid = (const int*)d_in[11];

    const int N = in_sizes[0] / 64;
    const int E = in_sizes[9];
    const int G = out_size / 4;
    const int NP = ((N + 63) / 64) * 64;
    const int NBIN = (N + 511) >> 9;          // coarse bins (<=256 for N<=131072)
    const int T = (E + TILE - 1) / TILE;      // build tiles

    char* ws = (char*)d_ws;
    size_t off = 0;
    auto alloc = [&](size_t bytes) -> void* {
        void* p = (void*)(ws + off);
        off += (bytes + 255) & ~(size_t)255;
        return p;
    };
    // sums/counts/cntD/cntS contiguous (all sizes multiples of 256B) -> one memset
    float* sums     = (float*)alloc(2048 * 4);   // 500*4 used
    float* counts   = (float*)alloc(512 * 4);
    int*   cntD     = (int*)alloc(256 * 4);
    int*   cntS     = (int*)alloc(256 * 4);
    int*   bucketD  = (int*)alloc((size_t)NBIN * SLOT * 4);
    unsigned short* bucketS = (unsigned short*)alloc((size_t)NBIN * SLOT * 2);
    int2*  edges    = (int2*)alloc((size_t)NBIN * SLOT * 8);
    int2*  rowBE    = (int2*)alloc((size_t)NP * 8);
    float* norm_out = (float*)alloc((size_t)NP * 4);
    float* norm_in  = (float*)alloc((size_t)NP * 4);
    float* region0  = (float*)alloc((size_t)N * 128 * 4);  // h1
    float* region1  = (float*)alloc((size_t)N * 64 * 4);   // agg1 / t2 / t3
    float* region2  = (float*)alloc((size_t)N * 64 * 4);   // h2 / t4

    hipMemsetAsync(sums, 0, (2048 + 512 + 256 + 256) * 4, stream);

    // ---- slotted atomic-light CSR build (3 kernels) ----
    k_buildbins<<<T, 256, 0, stream>>>(src, dst, E, NBIN, cntD, cntS, bucketD, bucketS);
    k_degout<<<NBIN, 256, 0, stream>>>(bucketS, cntS, N, norm_out);
    k_build<<<NBIN, 256, 0, stream>>>(bucketD, cntD, norm_out, N, rowBE, norm_in, edges);

    int nb = (N + 255) / 256;
    int gb = (N + 127) / 128;
    // L1: agg(x) -> region1 ; h1 = relu((agg*norm_in)@W1+b1) -> region0
    k_agg<64, false><<<(N + 15) / 16, 256, 0, stream>>>((const float4*)x, edges, rowBE, N,
                                                        (float4*)region1, nullptr, nullptr);
    k_gemm<64, 128, 8, 8, true, true><<<gb, 256, 0, stream>>>(region1, W1, b1, norm_in, N, region0);
    // L2: t2 = h1@W2 -> region1 ; h2 = relu(agg(t2)*norm+b2) -> region2 (fused epi)
    k_gemm<128, 64, 8, 4, false, false><<<gb, 256, 0, stream>>>(region0, W2, nullptr, nullptr, N, region1);
    k_agg<64, true><<<(N + 15) / 16, 256, 0, stream>>>((const float4*)region1, edges, rowBE, N,
                                                       (float4*)region2, norm_in, (const float4*)b2);
    // L3: t3 = h2@W3 -> region1 ; t4 = relu(agg(t3)*norm+b3)@W4 -> region2 (h3 never stored)
    k_gemm<64, 32, 4, 4, false, false><<<gb, 256, 0, stream>>>(region2, W3, nullptr, nullptr, N, region1);
    k_aggw4<<<(N + 31) / 32, 256, 0, stream>>>((const float4*)region1, edges, rowBE,
                                               norm_in, (const float4*)b3, W4, N,
                                               (float4*)region2);
    // L4: fused gather(t4)+norm+bias+pool
    k_aggpool<<<nb, 256, 0, stream>>>((const float4*)region2, edges, rowBE,
                                      norm_in, b4, gid, N, sums, counts);
    k_div<<<(G * 4 + 255) / 256, 256, 0, stream>>>(sums, counts, G, (float*)d_out);
}

// Round 9
// 300.837 us; speedup vs baseline: 1.0382x; 1.0382x over previous
//
#include <hip/hip_runtime.h>
#include <hip/hip_bf16.h>

// ---------------------------------------------------------------------------
// GCN 4-layer forward on MI355X.
//   - R6: single-pass SLOTTED CSR build (one device atomic per (bin,tile)).
//   - R6: k_w4 fused into agg3 (h3 never materialized).
//   - R5: float4 gathers (D/4 lanes/node), agg epilogue fusion.
//   - R7: k_agg 8-edge unroll (kept — helped ~25us).
//   - R8: REVERT GEMM to R6 4x4 microtile. R7's 8x8/8x4 tile hit 2.8M LDS
//     bank conflicts (Wlds stride-8-float reads = 4-way conflict) + 66KB LDS
//     dropped occupancy to 12-16% -> 42us/dispatch vs 24us for 4x4.
//   - pool: wave segmented scan on sorted gid (R1: contended atomics 152us).
// ---------------------------------------------------------------------------

#define TILE 4096   // edges per build tile (256 threads x 16)
#define SLOT 8192   // per-bin slot capacity (bin = 512 nodes, mean ~4080 edges)

// --- build pass 1: tile->LDS, histogram, reserve slot space, scatter -------
__global__ __launch_bounds__(256) void k_buildbins(
        const int* __restrict__ src, const int* __restrict__ dst, int E, int NBIN,
        int* __restrict__ cntD, int* __restrict__ cntS,
        int* __restrict__ bucketD, unsigned short* __restrict__ bucketS) {
    __shared__ int ssrc[TILE];
    __shared__ int sdst[TILE];
    __shared__ int hD[256], hS[256], bD[256], bS[256];
    int t = threadIdx.x;
    hD[t] = 0; hS[t] = 0;
    __syncthreads();
    int base = blockIdx.x * TILE;
    int lim = min(TILE, E - base);
#pragma unroll
    for (int k = 0; k < TILE / 256; k++) {
        int i = k * 256 + t;
        if (i < lim) {
            int d = dst[base + i], sv = src[base + i];
            sdst[i] = d; ssrc[i] = sv;
            atomicAdd(&hD[d >> 9], 1);
            atomicAdd(&hS[sv >> 9], 1);
        }
    }
    __syncthreads();
    if (t < NBIN) {
        bD[t] = (hD[t] > 0) ? atomicAdd(&cntD[t], hD[t]) : 0;
        bS[t] = (hS[t] > 0) ? atomicAdd(&cntS[t], hS[t]) : 0;
        hD[t] = 0; hS[t] = 0;
    }
    __syncthreads();
#pragma unroll
    for (int k = 0; k < TILE / 256; k++) {
        int i = k * 256 + t;
        if (i < lim) {
            int d = sdst[i], sv = ssrc[i];
            int binD = d >> 9, binS = sv >> 9;
            int pD = atomicAdd(&hD[binD], 1) + bD[binD];
            bucketD[binD * SLOT + pD] = (sv << 9) | (d & 511);
            int pS = atomicAdd(&hS[binS], 1) + bS[binS];
            bucketS[binS * SLOT + pS] = (unsigned short)(sv & 511);
        }
    }
}

// --- build pass 2: per-src-bucket LDS count -> norm_out --------------------
__global__ __launch_bounds__(256) void k_degout(const unsigned short* __restrict__ bucketS,
                                                const int* __restrict__ cntS,
                                                int N, float* __restrict__ norm_out) {
    __shared__ int cnt[512];
    int t = threadIdx.x;
    cnt[t] = 0; cnt[t + 256] = 0;
    __syncthreads();
    int bin = blockIdx.x;
    int b0 = bin * SLOT, cn = cntS[bin];
    for (int j = t; j < cn; j += 256) atomicAdd(&cnt[bucketS[b0 + j]], 1);
    __syncthreads();
    int base = bin << 9;
    for (int l = t; l < 512; l += 256) {
        int g = base + l;
        if (g < N) norm_out[g] = rsqrtf(fmaxf((float)cnt[l], 1.0f));
    }
}

// --- build pass 3: per-dst-bucket count+scan -> rowBE/norm_in, place edges -
__global__ __launch_bounds__(256) void k_build(const int* __restrict__ bucketD,
                                               const int* __restrict__ cntDg,
                                               const float* __restrict__ norm_out,
                                               int N, int2* __restrict__ rowBE,
                                               float* __restrict__ norm_in,
                                               int2* __restrict__ edges) {
    __shared__ int cnt[512], sc[512];
    int t = threadIdx.x;
    cnt[t] = 0; cnt[t + 256] = 0;
    __syncthreads();
    int bin = blockIdx.x;
    int b0 = bin * SLOT, cn = cntDg[bin];
    for (int j = t; j < cn; j += 256) atomicAdd(&cnt[bucketD[b0 + j] & 511], 1);
    __syncthreads();
    sc[t] = cnt[t]; sc[t + 256] = cnt[t + 256];
    __syncthreads();
    for (int off = 1; off < 512; off <<= 1) {
        int v0 = (t >= off) ? sc[t - off] : 0;
        int i1 = t + 256;
        int v1 = sc[i1 - off];   // i1 >= 256 >= off always
        __syncthreads();
        sc[t] += v0; sc[i1] += v1;
        __syncthreads();
    }
    int base = bin << 9;
    for (int l = t; l < 512; l += 256) {
        int g = base + l;
        int e = sc[l] - cnt[l];          // exclusive within bucket
        if (g < N) {
            rowBE[g] = make_int2(b0 + e, b0 + sc[l]);
            norm_in[g] = rsqrtf(fmaxf((float)cnt[l], 1.0f));
        }
        cnt[l] = e;                      // becomes placement cursor
    }
    __syncthreads();
    for (int j = t; j < cn; j += 256) {
        int p = bucketD[b0 + j];
        int sv = p >> 9, dl = p & 511;
        int pos = atomicAdd(&cnt[dl], 1);
        edges[b0 + pos] = make_int2(sv, __float_as_int(norm_out[sv]));
    }
}

// gather aggregation, float4 lanes: G = D/4 lanes per node, 8-edge unroll.
// EPI: out = relu(acc * norm[node] + bias4[lane])
template <int D, bool EPI>
__global__ __launch_bounds__(256) void k_agg(const float4* __restrict__ h4,
                                             const int2* __restrict__ edges,
                                             const int2* __restrict__ rowBE, int n,
                                             float4* __restrict__ out4,
                                             const float* __restrict__ norm,
                                             const float4* __restrict__ bias4) {
    constexpr int G = D / 4;           // lanes per node
    const int per = 256 / G;           // nodes per block
    int node = blockIdx.x * per + threadIdx.x / G;
    int lane = threadIdx.x % G;
    if (node >= n) return;
    int2 be = rowBE[node];
    int j = be.x, end = be.y;
    float4 acc = make_float4(0.f, 0.f, 0.f, 0.f);
    for (; j + 7 < end; j += 8) {
        int2 e[8];
        float4 v[8];
#pragma unroll
        for (int q = 0; q < 8; q++) e[q] = edges[j + q];
#pragma unroll
        for (int q = 0; q < 8; q++) v[q] = h4[(size_t)e[q].x * G + lane];
#pragma unroll
        for (int q = 0; q < 8; q++) {
            float wq = __int_as_float(e[q].y);
            acc.x += v[q].x * wq;
            acc.y += v[q].y * wq;
            acc.z += v[q].z * wq;
            acc.w += v[q].w * wq;
        }
    }
    if (j + 3 < end) {
        int2 e0 = edges[j];
        int2 e1 = edges[j + 1];
        int2 e2 = edges[j + 2];
        int2 e3 = edges[j + 3];
        float4 v0 = h4[(size_t)e0.x * G + lane];
        float4 v1 = h4[(size_t)e1.x * G + lane];
        float4 v2 = h4[(size_t)e2.x * G + lane];
        float4 v3 = h4[(size_t)e3.x * G + lane];
        float w0 = __int_as_float(e0.y), w1 = __int_as_float(e1.y);
        float w2 = __int_as_float(e2.y), w3 = __int_as_float(e3.y);
        acc.x += v0.x * w0 + v1.x * w1 + v2.x * w2 + v3.x * w3;
        acc.y += v0.y * w0 + v1.y * w1 + v2.y * w2 + v3.y * w3;
        acc.z += v0.z * w0 + v1.z * w1 + v2.z * w2 + v3.z * w3;
        acc.w += v0.w * w0 + v1.w * w1 + v2.w * w2 + v3.w * w3;
        j += 4;
    }
    for (; j < end; j++) {
        int2 e = edges[j];
        float4 v = h4[(size_t)e.x * G + lane];
        float w0 = __int_as_float(e.y);
        acc.x += v.x * w0; acc.y += v.y * w0; acc.z += v.z * w0; acc.w += v.w * w0;
    }
    if (EPI) {
        float s = norm[node];
        float4 b = bias4[lane];
        acc.x = fmaxf(acc.x * s + b.x, 0.f);
        acc.y = fmaxf(acc.y * s + b.y, 0.f);
        acc.z = fmaxf(acc.z * s + b.z, 0.f);
        acc.w = fmaxf(acc.w * s + b.w, 0.f);
    }
    out4[(size_t)node * G + lane] = acc;
}

// agg3 + W4 fused (D=32): h3 = relu(agg(t3)*norm+b3) in regs (never stored),
// t4[node] = h3 @ W4 via per-lane partials + 8-lane __shfl_xor reduce.
__global__ __launch_bounds__(256) void k_aggw4(const float4* __restrict__ h4,
                        const int2* __restrict__ edges, const int2* __restrict__ rowBE,
                        const float* __restrict__ norm, const float4* __restrict__ b3_4,
                        const float* __restrict__ W4, int n, float4* __restrict__ t4) {
    __shared__ float w[128];
    if (threadIdx.x < 128) w[threadIdx.x] = W4[threadIdx.x];
    __syncthreads();
    int node = blockIdx.x * 32 + threadIdx.x / 8;
    int lane = threadIdx.x % 8;
    if (node >= n) return;
    float4 wr0 = ((const float4*)w)[4 * lane + 0];
    float4 wr1 = ((const float4*)w)[4 * lane + 1];
    float4 wr2 = ((const float4*)w)[4 * lane + 2];
    float4 wr3 = ((const float4*)w)[4 * lane + 3];
    int2 be = rowBE[node];
    int j = be.x, end = be.y;
    float4 acc = make_float4(0.f, 0.f, 0.f, 0.f);
    for (; j + 3 < end; j += 4) {
        int2 e0 = edges[j];
        int2 e1 = edges[j + 1];
        int2 e2 = edges[j + 2];
        int2 e3 = edges[j + 3];
        float4 v0 = h4[(size_t)e0.x * 8 + lane];
        float4 v1 = h4[(size_t)e1.x * 8 + lane];
        float4 v2 = h4[(size_t)e2.x * 8 + lane];
        float4 v3 = h4[(size_t)e3.x * 8 + lane];
        float w0 = __int_as_float(e0.y), w1 = __int_as_float(e1.y);
        float w2 = __int_as_float(e2.y), w3 = __int_as_float(e3.y);
        acc.x += v0.x * w0 + v1.x * w1 + v2.x * w2 + v3.x * w3;
        acc.y += v0.y * w0 + v1.y * w1 + v2.y * w2 + v3.y * w3;
        acc.z += v0.z * w0 + v1.z * w1 + v2.z * w2 + v3.z * w3;
        acc.w += v0.w * w0 + v1.w * w1 + v2.w * w2 + v3.w * w3;
    }
    for (; j < end; j++) {
        int2 e = edges[j];
        float4 v = h4[(size_t)e.x * 8 + lane];
        float w0 = __int_as_float(e.y);
        acc.x += v.x * w0; acc.y += v.y * w0; acc.z += v.z * w0; acc.w += v.w * w0;
    }
    float s = norm[node];
    float4 b = b3_4[lane];
    float hx = fmaxf(acc.x * s + b.x, 0.f);
    float hy = fmaxf(acc.y * s + b.y, 0.f);
    float hz = fmaxf(acc.z * s + b.z, 0.f);
    float hw = fmaxf(acc.w * s + b.w, 0.f);
    float4 p;
    p.x = hx * wr0.x + hy * wr1.x + hz * wr2.x + hw * wr3.x;
    p.y = hx * wr0.y + hy * wr1.y + hz * wr2.y + hw * wr3.y;
    p.z = hx * wr0.z + hy * wr1.z + hz * wr2.z + hw * wr3.z;
    p.w = hx * wr0.w + hy * wr1.w + hz * wr2.w + hw * wr3.w;
#pragma unroll
    for (int m = 1; m < 8; m <<= 1) {
        p.x += __shfl_xor(p.x, m);
        p.y += __shfl_xor(p.y, m);
        p.z += __shfl_xor(p.z, m);
        p.w += __shfl_xor(p.w, m);
    }
    if (lane == 0) t4[node] = p;
}

// out[N x M] = op(A[N x K] (optionally row-scaled by norm)) @ W[K x M] (+bias, relu)
// R6-proven 4x4 microtile, W + transposed-A in LDS.
template <int K, int M, bool PRESCALE, bool BIAS_RELU>
__global__ __launch_bounds__(256) void k_gemm(const float* __restrict__ A,
                                              const float* __restrict__ W,
                                              const float* __restrict__ bias,
                                              const float* __restrict__ norm, int N,
                                              float* __restrict__ out) {
    constexpr int CT   = M / 4;        // col threads
    constexpr int RTH  = 256 / CT;     // row threads
    constexpr int ROWS = RTH * 4;      // rows per block
    constexpr int KC   = (K > 64) ? 64 : K;
    constexpr int APAD = ROWS + 4;
    __shared__ float Alds[KC * APAD];  // transposed: Alds[k][r]
    __shared__ float Wlds[KC * M];
    int t  = threadIdx.x;
    int tx = t % CT;
    int ty = t / CT;
    int row0 = blockIdx.x * ROWS;
    float acc[4][4] = {};
    for (int kc = 0; kc < K; kc += KC) {
        for (int idx = t; idx < KC * M / 4; idx += 256)
            ((float4*)Wlds)[idx] = ((const float4*)(W + kc * M))[idx];
        constexpr int A4 = ROWS * KC / 4;
        for (int idx = t; idx < A4; idx += 256) {
            int r  = idx / (KC / 4);
            int k4 = idx % (KC / 4);
            int grow = row0 + r;
            float4 v = make_float4(0.f, 0.f, 0.f, 0.f);
            if (grow < N) {
                v = *(const float4*)(A + (size_t)grow * K + kc + k4 * 4);
                if (PRESCALE) {
                    float s = norm[grow];
                    v.x *= s; v.y *= s; v.z *= s; v.w *= s;
                }
            }
            Alds[(k4 * 4 + 0) * APAD + r] = v.x;
            Alds[(k4 * 4 + 1) * APAD + r] = v.y;
            Alds[(k4 * 4 + 2) * APAD + r] = v.z;
            Alds[(k4 * 4 + 3) * APAD + r] = v.w;
        }
        __syncthreads();
#pragma unroll 8
        for (int k = 0; k < KC; k++) {
            float4 a = *(const float4*)&Alds[k * APAD + ty * 4];
            float4 w = *(const float4*)&Wlds[k * M + tx * 4];
            acc[0][0] += a.x * w.x; acc[0][1] += a.x * w.y; acc[0][2] += a.x * w.z; acc[0][3] += a.x * w.w;
            acc[1][0] += a.y * w.x; acc[1][1] += a.y * w.y; acc[1][2] += a.y * w.z; acc[1][3] += a.y * w.w;
            acc[2][0] += a.z * w.x; acc[2][1] += a.z * w.y; acc[2][2] += a.z * w.z; acc[2][3] += a.z * w.w;
            acc[3][0] += a.w * w.x; acc[3][1] += a.w * w.y; acc[3][2] += a.w * w.z; acc[3][3] += a.w * w.w;
        }
        __syncthreads();
    }
#pragma unroll
    for (int i = 0; i < 4; i++) {
        int grow = row0 + ty * 4 + i;
        if (grow < N) {
            float4 o = make_float4(acc[i][0], acc[i][1], acc[i][2], acc[i][3]);
            if (BIAS_RELU) {
                float4 b = *(const float4*)(bias + tx * 4);
                o.x = fmaxf(o.x + b.x, 0.f);
                o.y = fmaxf(o.y + b.y, 0.f);
                o.z = fmaxf(o.z + b.z, 0.f);
                o.w = fmaxf(o.w + b.w, 0.f);
            }
            *(float4*)(out + (size_t)grow * M + tx * 4) = o;
        }
    }
}

// L4 fused: per node (1 thread): acc = sum_e t4[src_e]*norm_out_e ;
// v = acc*norm_in + b4 ; wave segmented-scan pool on sorted gid -> atomics
__global__ __launch_bounds__(256) void k_aggpool(const float4* __restrict__ t4,
                        const int2* __restrict__ edges, const int2* __restrict__ rowBE,
                        const float* __restrict__ norm, const float* __restrict__ b4,
                        const int* __restrict__ gid, int N,
                        float* __restrict__ sums, float* __restrict__ counts) {
    int n = blockIdx.x * blockDim.x + threadIdx.x;
    int lane = threadIdx.x & 63;
    bool valid = (n < N);
    float v0 = 0.f, v1 = 0.f, v2 = 0.f, v3 = 0.f, cnt = 0.f;
    int g = -1;
    if (valid) {
        g = gid[n];
        int2 be = rowBE[n];
        int j = be.x, end = be.y;
        float4 acc = make_float4(0.f, 0.f, 0.f, 0.f);
        for (; j + 3 < end; j += 4) {
            int2 e0 = edges[j];
            int2 e1 = edges[j + 1];
            int2 e2 = edges[j + 2];
            int2 e3 = edges[j + 3];
            float4 x0 = t4[e0.x];
            float4 x1 = t4[e1.x];
            float4 x2 = t4[e2.x];
            float4 x3 = t4[e3.x];
            float w0 = __int_as_float(e0.y), w1 = __int_as_float(e1.y);
            float w2 = __int_as_float(e2.y), w3 = __int_as_float(e3.y);
            acc.x += x0.x * w0 + x1.x * w1 + x2.x * w2 + x3.x * w3;
            acc.y += x0.y * w0 + x1.y * w1 + x2.y * w2 + x3.y * w3;
            acc.z += x0.z * w0 + x1.z * w1 + x2.z * w2 + x3.z * w3;
            acc.w += x0.w * w0 + x1.w * w1 + x2.w * w2 + x3.w * w3;
        }
        for (; j < end; j++) {
            int2 e = edges[j];
            float4 x = t4[e.x];
            float w0 = __int_as_float(e.y);
            acc.x += x.x * w0; acc.y += x.y * w0; acc.z += x.z * w0; acc.w += x.w * w0;
        }
        float s = norm[n];
        v0 = acc.x * s + b4[0];
        v1 = acc.y * s + b4[1];
        v2 = acc.z * s + b4[2];
        v3 = acc.w * s + b4[3];
        cnt = 1.f;
    }
    // segmented inclusive scan across the 64-lane wave (gid sorted)
#pragma unroll
    for (int off = 1; off < 64; off <<= 1) {
        float u0 = __shfl_up(v0, off);
        float u1 = __shfl_up(v1, off);
        float u2 = __shfl_up(v2, off);
        float u3 = __shfl_up(v3, off);
        float uc = __shfl_up(cnt, off);
        int   ug = __shfl_up(g, off);
        if (lane >= off && ug == g) { v0 += u0; v1 += u1; v2 += u2; v3 += u3; cnt += uc; }
    }
    int gnext = __shfl_down(g, 1);
    bool boundary = (lane == 63) || (gnext != g);
    if (boundary && valid) {
        atomicAdd(&sums[g * 4 + 0], v0);
        atomicAdd(&sums[g * 4 + 1], v1);
        atomicAdd(&sums[g * 4 + 2], v2);
        atomicAdd(&sums[g * 4 + 3], v3);
        atomicAdd(&counts[g], cnt);
    }
}

__global__ void k_div(const float* __restrict__ sums, const float* __restrict__ counts,
                      int G, float* __restrict__ out) {
    int idx = blockIdx.x * blockDim.x + threadIdx.x;
    if (idx >= G * 4) return;
    out[idx] = sums[idx] / fmaxf(counts[idx >> 2], 1.0f);
}

extern "C" void kernel_launch(void* const* d_in, const int* in_sizes, int n_in,
                              void* d_out, int out_size, void* d_ws, size_t ws_size,
                              hipStream_t stream) {
    const float* x  = (const float*)d_in[0];
    const float* W1 = (const float*)d_in[1];
    const float* b1 = (const float*)d_in[2];
    const float* W2 = (const float*)d_in[3];
    const float* b2 = (const float*)d_in[4];
    const float* W3 = (const float*)d_in[5];
    const float* b3 = (const float*)d_in[6];
    const float* W4 = (const float*)d_in[7];
    const float* b4 = (const float*)d_in[8];
    const int* src = (const int*)d_in[9];
    const int* dst = (const int*)d_in[10];
    const int* gid = (const int*)d_in[11];

    const int N = in_sizes[0] / 64;
    const int E = in_sizes[9];
    const int G = out_size / 4;
    const int NP = ((N + 63) / 64) * 64;
    const int NBIN = (N + 511) >> 9;          // coarse bins (<=256 for N<=131072)
    const int T = (E + TILE - 1) / TILE;      // build tiles

    char* ws = (char*)d_ws;
    size_t off = 0;
    auto alloc = [&](size_t bytes) -> void* {
        void* p = (void*)(ws + off);
        off += (bytes + 255) & ~(size_t)255;
        return p;
    };
    // sums/counts/cntD/cntS contiguous (all sizes multiples of 256B) -> one memset
    float* sums     = (float*)alloc(2048 * 4);   // 500*4 used
    float* counts   = (float*)alloc(512 * 4);
    int*   cntD     = (int*)alloc(256 * 4);
    int*   cntS     = (int*)alloc(256 * 4);
    int*   bucketD  = (int*)alloc((size_t)NBIN * SLOT * 4);
    unsigned short* bucketS = (unsigned short*)alloc((size_t)NBIN * SLOT * 2);
    int2*  edges    = (int2*)alloc((size_t)NBIN * SLOT * 8);
    int2*  rowBE    = (int2*)alloc((size_t)NP * 8);
    float* norm_out = (float*)alloc((size_t)NP * 4);
    float* norm_in  = (float*)alloc((size_t)NP * 4);
    float* region0  = (float*)alloc((size_t)N * 128 * 4);  // h1
    float* region1  = (float*)alloc((size_t)N * 64 * 4);   // agg1 / t2 / t3
    float* region2  = (float*)alloc((size_t)N * 64 * 4);   // h2 / t4

    hipMemsetAsync(sums, 0, (2048 + 512 + 256 + 256) * 4, stream);

    // ---- slotted atomic-light CSR build (3 kernels) ----
    k_buildbins<<<T, 256, 0, stream>>>(src, dst, E, NBIN, cntD, cntS, bucketD, bucketS);
    k_degout<<<NBIN, 256, 0, stream>>>(bucketS, cntS, N, norm_out);
    k_build<<<NBIN, 256, 0, stream>>>(bucketD, cntD, norm_out, N, rowBE, norm_in, edges);

    int nb = (N + 255) / 256;
    // L1: agg(x) -> region1 ; h1 = relu((agg*norm_in)@W1+b1) -> region0
    k_agg<64, false><<<(N + 15) / 16, 256, 0, stream>>>((const float4*)x, edges, rowBE, N,
                                                        (float4*)region1, nullptr, nullptr);
    k_gemm<64, 128, true, true><<<(N + 31) / 32, 256, 0, stream>>>(region1, W1, b1, norm_in, N, region0);
    // L2: t2 = h1@W2 -> region1 ; h2 = relu(agg(t2)*norm+b2) -> region2 (fused epi)
    k_gemm<128, 64, false, false><<<(N + 63) / 64, 256, 0, stream>>>(region0, W2, nullptr, nullptr, N, region1);
    k_agg<64, true><<<(N + 15) / 16, 256, 0, stream>>>((const float4*)region1, edges, rowBE, N,
                                                       (float4*)region2, norm_in, (const float4*)b2);
    // L3: t3 = h2@W3 -> region1 ; t4 = relu(agg(t3)*norm+b3)@W4 -> region2 (h3 never stored)
    k_gemm<64, 32, false, false><<<(N + 127) / 128, 256, 0, stream>>>(region2, W3, nullptr, nullptr, N, region1);
    k_aggw4<<<(N + 31) / 32, 256, 0, stream>>>((const float4*)region1, edges, rowBE,
                                               norm_in, (const float4*)b3, W4, N,
                                               (float4*)region2);
    // L4: fused gather(t4)+norm+bias+pool
    k_aggpool<<<nb, 256, 0, stream>>>((const float4*)region2, edges, rowBE,
                                      norm_in, b4, gid, N, sums, counts);
    k_div<<<(G * 4 + 255) / 256, 256, 0, stream>>>(sums, counts, G, (float*)d_out);
}